// Round 6
// baseline (979.215 us; speedup 1.0000x reference)
//
#include <hip/hip_runtime.h>
#include <math.h>

// Problem constants
#define kH  1024
#define kB  64
#define kS  256
#define kV  10000
#define kH3 3072

// ---------------- helpers ----------------
__device__ __forceinline__ float warp_sum(float v) {
#pragma unroll
  for (int off = 32; off > 0; off >>= 1) v += __shfl_down(v, off, 64);
  return v;  // valid on lane 0
}
__device__ __forceinline__ float warp_sum_all(float v) {
#pragma unroll
  for (int off = 32; off > 0; off >>= 1) v += __shfl_xor(v, off, 64);
  return v;  // valid on ALL lanes
}
__device__ __forceinline__ float warp_max_all(float v) {
#pragma unroll
  for (int off = 32; off > 0; off >>= 1) v = fmaxf(v, __shfl_xor(v, off, 64));
  return v;
}
__device__ __forceinline__ float sigmoidf_(float x) { return 1.0f / (1.0f + __expf(-x)); }

// ---------------- GIp[r][t] = (emb[seq[t]] . W_ih[r]) + b_ih[r] ----------------
// v2: 192 blocks x 512 threads. Block owns 16 rows (wave w: rows bid*16+2w+{0,1}).
// emb row staged in double-buffered LDS once per t (shared by 8 waves):
// emb L2 traffic 786 MB -> 49 MB vs r5. Weights in VGPRs [u*64+lane] layout.
__global__ __launch_bounds__(512) void k_gi(const int* __restrict__ seq,
    const float* __restrict__ emb, const float* __restrict__ W_ih,
    const float* __restrict__ b_ih, float* __restrict__ GIp) {
  __shared__ float xs[2][kH];
  __shared__ int seqs[kB];
  const int tid = threadIdx.x, lane = tid & 63, w = tid >> 6;  // w 0..7
  const int r0 = blockIdx.x * 16 + 2 * w;
  if (tid < kB) seqs[tid] = seq[tid];
  float wv[2][16];
#pragma unroll
  for (int i = 0; i < 2; ++i) {
    const float* p = W_ih + (size_t)(r0 + i) * kH + lane;
#pragma unroll
    for (int u = 0; u < 16; ++u) wv[i][u] = p[u * 64];
  }
  const float b0 = b_ih[r0], b1 = b_ih[r0 + 1];
  __syncthreads();  // seqs ready
  for (int t = 0; t < kB; ++t) {
    const int p = t & 1;
    const int tok = seqs[t];
    // stage emb row: 512 threads x float2 = 4 KB, coalesced
    ((float2*)xs[p])[tid] = ((const float2*)(emb + (size_t)tok * kH))[tid];
    __syncthreads();  // stage complete (double-buffer -> one barrier per t)
    float a0 = 0.f, a1 = 0.f;
#pragma unroll
    for (int u = 0; u < 16; ++u) {
      const float x = xs[p][u * 64 + lane];
      a0 += wv[0][u] * x; a1 += wv[1][u] * x;
    }
    a0 = warp_sum(a0); a1 = warp_sum(a1);
    if (lane == 0) {
      GIp[(size_t)r0 * kB + t] = a0 + b0;
      GIp[(size_t)(r0 + 1) * kB + t] = a1 + b1;
    }
  }
}

// ---------------- Persistent GRU scan, v6 ----------------
// 64 blocks x 256 threads (4 waves). Wave w owns h[bid*16+4w .. +3]
// (12 weight rows -> 192 VGPR/thread). Handshake, per r4/r5 lessons
// (atomic loads = 1 MALL line txn each; block barrier + flag hop = 2 RTs):
//  - producer WAVE: lanes 0-3 store 4 tagged u64 values (one predicated
//    instr) + rnn, s_waitcnt(0) to retire them, then lane0 stores a
//    per-wave-group sentinel sen[t][g] (g = bid*4+w; 256 u32 = 16 lines).
//    No block barrier before publish.
//  - consumer thread tid: polls sen[t-1][tid] (4 pollers/line, s_sleep
//    backoff), then fetches its 4 tagged values (tag-verified spin
//    fallback -> correctness doesn't depend on the waitcnt ordering).
//  - LDS h double-buffered: ONE barrier per step.
__global__ __launch_bounds__(256) void k_gru(const float* __restrict__ h0,
    const float* __restrict__ W_hh, const float* __restrict__ b_hh,
    const float* __restrict__ GIp, float* __restrict__ rnn,
    unsigned long long* __restrict__ step, unsigned* __restrict__ sen) {
  __shared__ float gis[3 * 16 * kB];  // 12 KB: [gate][jj][t]
  __shared__ float hs[2][kH];         // 8 KB double-buffered h
  const int tid = threadIdx.x, lane = tid & 63, w = tid >> 6;  // w 0..3
  const int bid = blockIdx.x;
  const int j0 = bid * 16;
  const int jw = j0 + 4 * w;          // wave's 4-h base
  const int q = lane & 3;             // lane's output index within the wave
  const int jq = jw + q;              // h index computed by lanes 0..3

  for (int idx = tid; idx < 3 * 16 * kB; idx += 256) {
    const int gate = idx >> 10, rem = idx & 1023;  // rem = jj*64 + t
    gis[idx] = GIp[(size_t)(gate * kH + j0) * kB + rem];
  }

  // 12 weight rows: rows[3i+g] = g*kH + jw + i  (i 0..3, g 0..2)
  float wv[12][16];
#pragma unroll
  for (int i = 0; i < 4; ++i) {
#pragma unroll
    for (int g = 0; g < 3; ++g) {
      const float* p = W_hh + (size_t)(g * kH + jw + i) * kH + lane;
#pragma unroll
      for (int u = 0; u < 16; ++u) wv[i * 3 + g][u] = p[u * 64];
    }
  }
  const float bhr = b_hh[jq], bhz = b_hh[kH + jq], bhn = b_hh[2 * kH + jq];
  float cur = h0[jq];  // h_old for lanes 0..3
  __syncthreads();     // gis ready

  for (int t = 0; t < kB; ++t) {
    const int p = t & 1;
    if (t == 0) {
      *(float4*)&hs[0][4 * tid] = *(const float4*)(h0 + 4 * tid);
    } else {
      const unsigned want = (unsigned)t;
      // detect: poll my wave-group sentinel
      while (true) {
        const unsigned f = __hip_atomic_load(&sen[(size_t)(t - 1) * 256 + tid],
            __ATOMIC_RELAXED, __HIP_MEMORY_SCOPE_AGENT);
        if (f == want) break;
        __builtin_amdgcn_s_sleep(1);
      }
      // fetch my 4 tagged values (tag-verified fallback)
      const unsigned long long* sb = step + (size_t)(t - 1) * kH + 4 * tid;
      float v[4];
#pragma unroll
      for (int c = 0; c < 4; ++c) {
        unsigned long long x = __hip_atomic_load(&sb[c], __ATOMIC_RELAXED,
                                                 __HIP_MEMORY_SCOPE_AGENT);
        while ((unsigned)(x >> 32) != want) {
          __builtin_amdgcn_s_sleep(1);
          x = __hip_atomic_load(&sb[c], __ATOMIC_RELAXED,
                                __HIP_MEMORY_SCOPE_AGENT);
        }
        v[c] = __uint_as_float((unsigned)x);
      }
      *(float4*)&hs[p][4 * tid] = make_float4(v[0], v[1], v[2], v[3]);
    }
    __syncthreads();  // staging complete (only barrier in the step)

    float hx[16];
#pragma unroll
    for (int u = 0; u < 16; ++u) hx[u] = hs[p][u * 64 + lane];

    float d[12];
#pragma unroll
    for (int i = 0; i < 12; ++i) {
      float a = 0.f;
#pragma unroll
      for (int u = 0; u < 16; ++u) a += wv[i][u] * hx[u];
      d[i] = a;
    }
#pragma unroll
    for (int i = 0; i < 12; ++i) d[i] = warp_sum_all(d[i]);

    if (lane < 4) {  // lane q computes h[jq]
      const float gr = gis[0 * 1024 + (4 * w + q) * kB + t];
      const float gz = gis[1 * 1024 + (4 * w + q) * kB + t];
      const float gn = gis[2 * 1024 + (4 * w + q) * kB + t];
      const float r = sigmoidf_(gr + d[q * 3 + 0] + bhr);
      const float z = sigmoidf_(gz + d[q * 3 + 1] + bhz);
      const float xn = gn + r * (d[q * 3 + 2] + bhn);
      const float e2 = __expf(2.f * xn);
      const float n = 1.f - 2.f / (e2 + 1.f);   // tanh
      const float hn = (1.f - z) * n + z * cur;
      cur = hn;
      __hip_atomic_store(&step[(size_t)t * kH + jq],
          (((unsigned long long)(t + 1)) << 32) | __float_as_uint(hn),
          __ATOMIC_RELAXED, __HIP_MEMORY_SCOPE_AGENT);
      rnn[(size_t)t * kH + jq] = hn;
    }
    __builtin_amdgcn_s_waitcnt(0);  // retire value stores before sentinel
    if (lane == 0)
      __hip_atomic_store(&sen[(size_t)t * 256 + bid * 4 + w],
          (unsigned)(t + 1), __ATOMIC_RELAXED, __HIP_MEMORY_SCOPE_AGENT);
  }
}

// ---------------- w2h stage A: coalesced partials ---------------- grid 64x256
__global__ __launch_bounds__(256) void k_w2hp(const float* __restrict__ W_attn,
    const float* __restrict__ v_attn, float* __restrict__ p2) {
  const int p = blockIdx.x, t = threadIdx.x;
  float ax = 0, ay = 0, az = 0, aw = 0;
#pragma unroll 4
  for (int hh = 0; hh < 16; ++hh) {
    const int h = p * 16 + hh;
    const float vh = v_attn[h];
    const float4 wq = *(const float4*)(W_attn + (size_t)h * 2048 + kH + 4 * t);
    ax += vh * wq.x; ay += vh * wq.y; az += vh * wq.z; aw += vh * wq.w;
  }
  *(float4*)(p2 + (size_t)p * kH + 4 * t) = make_float4(ax, ay, az, aw);
}

// ---------------- w2h stage B + hidden-output copy ---------------- grid 4x256
__global__ __launch_bounds__(256) void k_w2hr(const float* __restrict__ p2,
    const float* __restrict__ rnn, float* __restrict__ w2h,
    float* __restrict__ hid) {
  const int k = blockIdx.x * 256 + threadIdx.x;
  float a = 0.f;
#pragma unroll 8
  for (int p = 0; p < 64; ++p) a += p2[(size_t)p * kH + k];
  w2h[k] = a;
  hid[k] = rnn[63 * kH + k];
}

// ---------------- scores[b][s] = enc[s][b][:] . w2h ----------------
__global__ __launch_bounds__(256) void k_scores(const float* __restrict__ enc,
    const float* __restrict__ w2h, float* __restrict__ sc) {
  const int lane = threadIdx.x & 63;
  const int wg = blockIdx.x * 4 + (threadIdx.x >> 6);  // 0..16383
  const int b = wg & 63, s = wg >> 6;
  const float4* ep = (const float4*)(enc + ((size_t)s * kB + b) * kH) + lane * 4;
  const float4* wp = (const float4*)w2h + lane * 4;
  float acc = 0.f;
#pragma unroll
  for (int c = 0; c < 4; ++c) {
    const float4 e = ep[c], wq = wp[c];
    acc += e.x * wq.x + e.y * wq.y + e.z * wq.z + e.w * wq.w;
  }
  acc = warp_sum(acc);
  if (lane == 0) sc[b * kS + s] = acc;
}

// ---------------- softmax (fused) + context partials ----------------
__global__ __launch_bounds__(256) void k_context(const float* __restrict__ enc,
    const float* __restrict__ sc, float* __restrict__ attn,
    float* __restrict__ part) {
  __shared__ float sm[4], ss[4], ap[kS];
  const int b = blockIdx.x & 63, ch = blockIdx.x >> 6;
  const int t = threadIdx.x, lane = t & 63, w = t >> 6;
  const float x = sc[b * kS + t];
  float m = warp_max_all(x);
  if (lane == 0) sm[w] = m;
  __syncthreads();
  m = fmaxf(fmaxf(sm[0], sm[1]), fmaxf(sm[2], sm[3]));
  const float e = __expf(x - m);
  float s = warp_sum_all(e);
  if (lane == 0) ss[w] = s;
  __syncthreads();
  s = ss[0] + ss[1] + ss[2] + ss[3];
  const float p = e / s;
  ap[t] = p;
  if (ch == 0) attn[b * kS + t] = p;
  __syncthreads();
  const int h0_ = t * 4;
  float ax = 0, ay = 0, az = 0, aw = 0;
  const int s0 = ch * 64;
  for (int si = s0; si < s0 + 64; ++si) {
    const float a = ap[si];
    const float4 v = *(const float4*)(enc + ((size_t)si * kB + b) * kH + h0_);
    ax += a * v.x; ay += a * v.y; az += a * v.z; aw += a * v.w;
  }
  *(float4*)(part + ((size_t)ch * kB + b) * kH + h0_) =
      make_float4(ax, ay, az, aw);
}

// ---------------- coT[i][b] = tanh([rnn,ctx][b] . W_concat[i] + b_c[i]) ----------------
__global__ __launch_bounds__(256) void k_concat(const float* __restrict__ rnn,
    const float* __restrict__ part, const float* __restrict__ W_c,
    const float* __restrict__ b_c, float* __restrict__ coT) {
  const int lane = threadIdx.x & 63;
  const int gw = blockIdx.x * 4 + (threadIdx.x >> 6);  // 0..8191
  const int i = gw >> 3, c = gw & 7;
  float wreg[32];
  {
    const float4* wp = (const float4*)(W_c + (size_t)i * 2048) + lane * 8;
#pragma unroll
    for (int cc = 0; cc < 8; ++cc) {
      const float4 f = wp[cc];
      wreg[cc * 4 + 0] = f.x; wreg[cc * 4 + 1] = f.y;
      wreg[cc * 4 + 2] = f.z; wreg[cc * 4 + 3] = f.w;
    }
  }
  const float bc = b_c[i];
  const int jcol = lane * 32;
  for (int bb = 0; bb < 8; ++bb) {
    const int b = c * 8 + bb;
    float acc = 0.f;
    if (jcol < kH) {
      const float* xr = rnn + (size_t)b * kH + jcol;
#pragma unroll
      for (int cc = 0; cc < 8; ++cc) {
        const float4 xv = *(const float4*)(xr + cc * 4);
        acc += wreg[cc * 4 + 0] * xv.x + wreg[cc * 4 + 1] * xv.y +
               wreg[cc * 4 + 2] * xv.z + wreg[cc * 4 + 3] * xv.w;
      }
    } else {
      const int hc = jcol - kH;
#pragma unroll
      for (int cc = 0; cc < 8; ++cc) {
        float4 xs = make_float4(0, 0, 0, 0);
#pragma unroll
        for (int ch = 0; ch < 4; ++ch) {
          const float4 pv = *(const float4*)(part +
              ((size_t)ch * kB + b) * kH + hc + cc * 4);
          xs.x += pv.x; xs.y += pv.y; xs.z += pv.z; xs.w += pv.w;
        }
        acc += wreg[cc * 4 + 0] * xs.x + wreg[cc * 4 + 1] * xs.y +
               wreg[cc * 4 + 2] * xs.z + wreg[cc * 4 + 3] * xs.w;
      }
    }
    acc = warp_sum(acc);
    if (lane == 0) coT[(size_t)i * kB + b] = tanhf(acc + bc);
  }
}

// ---------------- out[b][v] = coT[:,b] . W_out[v] + b_out[v] ----------------
// v6: 500 blocks x 256 threads, 20 v-rows/block (5/wave). coT staged in LDS
// k-chunks (coalesced), W_out read with per-lane VECTOR loads (v derives from
// threadIdx -> not provably uniform -> global_load broadcast, NOT s_load:
// avoids streaming 40 MB through the scalar/constant cache).
#define KC 128
__global__ __launch_bounds__(256) void k_out(const float* __restrict__ coT,
    const float* __restrict__ W_out, const float* __restrict__ b_out,
    float* __restrict__ out) {
  __shared__ float cs[KC * kB];  // 32 KB
  const int tid = threadIdx.x;
  const int b = tid & 63;
  const int vg = tid >> 6;                 // 0..3
  const int v0 = blockIdx.x * 20 + vg * 5; // 500*20 = 10000 exactly
  float acc[5];
#pragma unroll
  for (int i = 0; i < 5; ++i) acc[i] = 0.f;
  for (int k0 = 0; k0 < kH; k0 += KC) {
    // stage coT[k0..k0+KC)[all b]: contiguous 32 KB, 256 threads x 8 float4
    {
      const float4* src = (const float4*)(coT + (size_t)k0 * kB);
      float4* dst = (float4*)cs;
#pragma unroll
      for (int c = 0; c < KC * kB / 4 / 256; ++c)
        dst[tid + 256 * c] = src[tid + 256 * c];
    }
    __syncthreads();
    for (int kk = 0; kk < KC; kk += 4) {
      const float c0 = cs[(kk + 0) * kB + b];
      const float c1 = cs[(kk + 1) * kB + b];
      const float c2 = cs[(kk + 2) * kB + b];
      const float c3 = cs[(kk + 3) * kB + b];
#pragma unroll
      for (int i = 0; i < 5; ++i) {
        const float4 wq = *(const float4*)(W_out + (size_t)(v0 + i) * kH + k0 + kk);
        acc[i] += wq.x * c0 + wq.y * c1 + wq.z * c2 + wq.w * c3;
      }
    }
    __syncthreads();
  }
#pragma unroll
  for (int i = 0; i < 5; ++i)
    out[(size_t)b * kV + v0 + i] = acc[i] + b_out[v0 + i];
}

// ---------------- launcher ----------------
extern "C" void kernel_launch(void* const* d_in, const int* in_sizes, int n_in,
                              void* d_out, int out_size, void* d_ws,
                              size_t ws_size, hipStream_t stream) {
  const int*   seq    = (const int*)  d_in[0];
  const float* h0     = (const float*)d_in[1];
  const float* enc    = (const float*)d_in[2];
  const float* emb    = (const float*)d_in[3];
  const float* W_ih   = (const float*)d_in[4];
  const float* W_hh   = (const float*)d_in[5];
  const float* b_ih   = (const float*)d_in[6];
  const float* b_hh   = (const float*)d_in[7];
  const float* W_attn = (const float*)d_in[8];
  // d_in[9] = b_attn: drops out of softmax (shift invariance)
  const float* v_attn = (const float*)d_in[10];
  const float* W_conc = (const float*)d_in[11];
  const float* b_conc = (const float*)d_in[12];
  const float* W_outp = (const float*)d_in[13];
  const float* b_outp = (const float*)d_in[14];

  float* out      = (float*)d_out;           // (B,V) = 640000
  float* out_hid  = out + 640000;            // (1,1,H) = 1024
  float* out_attn = out + 641024;            // (B,1,S) = 16384

  float* ws = (float*)d_ws;
  float* GIp  = ws;                        // 196608
  float* RNN  = ws + 196608;               // -> 262144
  unsigned long long* STEP =
      (unsigned long long*)(ws + 262144);  // 64*1024 u64 -> 393216
  unsigned* SEN = (unsigned*)(ws + 393216); // 64*256 u32 -> 409600
  float* P2   = ws + 409600;               // -> 475136
  float* W2H  = ws + 475136;               // -> 476160
  float* SC   = ws + 476160;               // -> 492544
  float* PART = ws + 492544;               // -> 754688
  float* COT  = ws + 754688;               // -> 820224 floats (~3.3 MB)

  k_gi<<<192, 512, 0, stream>>>(seq, emb, W_ih, b_ih, GIp);
  k_gru<<<64, 256, 0, stream>>>(h0, W_hh, b_hh, GIp, RNN, STEP, SEN);
  k_w2hp<<<64, 256, 0, stream>>>(W_attn, v_attn, P2);
  k_w2hr<<<4, 256, 0, stream>>>(P2, RNN, W2H, out_hid);
  k_scores<<<4096, 256, 0, stream>>>(enc, W2H, SC);
  k_context<<<256, 256, 0, stream>>>(enc, SC, out_attn, PART);
  k_concat<<<2048, 256, 0, stream>>>(RNN, PART, W_conc, b_conc, COT);
  k_out<<<500, 256, 0, stream>>>(COT, W_outp, b_outp, out);
}